// Round 7
// baseline (318.826 us; speedup 1.0000x reference)
//
#include <hip/hip_runtime.h>

#define Bb 256
#define Nn 240
#define Ee 4338
#define Ff 28
#define Uu 100
#define Kk 128            // U + F
#define Mrows (Bb * Nn)   // 61440
#define ET (Ee + Nn)      // edges incl self-loops
#define AS 136            // LDS A-panel row stride in u16 (272B -> <=2-way bank alias)

typedef __attribute__((ext_vector_type(8))) short bf16x8;
typedef __attribute__((ext_vector_type(4))) float f32x4;
typedef unsigned short u16;

__device__ __forceinline__ float bf2f(u16 u) {
  union { unsigned int i; float f; } v; v.i = ((unsigned int)u) << 16; return v.f;
}
__device__ __forceinline__ u16 f2bf(float f) {
  union { float ff; unsigned int i; } v; v.ff = f;
  unsigned int x = v.i;
  return (u16)((x + 0x7fffu + ((x >> 16) & 1u)) >> 16);
}
__device__ __forceinline__ void split4(const float4 v, ushort4& h, ushort4& l) {
  u16 h0 = f2bf(v.x), h1 = f2bf(v.y), h2 = f2bf(v.z), h3 = f2bf(v.w);
  h.x = h0; h.y = h1; h.z = h2; h.w = h3;
  l.x = f2bf(v.x - bf2f(h0)); l.y = f2bf(v.y - bf2f(h1));
  l.z = f2bf(v.z - bf2f(h2)); l.w = f2bf(v.w - bf2f(h3));
}

// ---------------------------------------------------------------------------
// k_prep: fp32 weights -> padded/transposed bf16 hi/lo (unchanged).
// ---------------------------------------------------------------------------
__global__ __launch_bounds__(256) void k_prep(
    const float* __restrict__ Wg, const float* __restrict__ Wru, const float* __restrict__ Wc,
    u16* __restrict__ wgh, u16* __restrict__ wgl,
    u16* __restrict__ wruh, u16* __restrict__ wrul,
    u16* __restrict__ wch, u16* __restrict__ wcl) {
  int gt = blockIdx.x * 256 + threadIdx.x, GS = gridDim.x * 256;
  for (int i = gt; i < 128 * Kk; i += GS) {
    int c = i >> 7, k = i & 127;
    float v = (c < Uu) ? Wg[c * Kk + k] : 0.f;
    u16 h = f2bf(v); wgh[i] = h; wgl[i] = f2bf(v - bf2f(h));
  }
  for (int i = gt; i < 256 * Kk; i += GS) {
    int n = i >> 7, kp = i & 127;
    int k = (kp < Uu) ? (kp + Ff) : (kp - Uu);
    float v = (n < 2 * Uu) ? Wru[k * (2 * Uu) + n] : 0.f;
    u16 h = f2bf(v); wruh[i] = h; wrul[i] = f2bf(v - bf2f(h));
  }
  for (int i = gt; i < 128 * Kk; i += GS) {
    int n = i >> 7, kp = i & 127;
    int k = (kp < Uu) ? (kp + Ff) : (kp - Uu);
    float v = (n < Uu) ? Wc[k * Uu + n] : 0.f;
    u16 h = f2bf(v); wch[i] = h; wcl[i] = f2bf(v - bf2f(h));
  }
}

// ---------------------------------------------------------------------------
// k_csr: dst-grouped CSR (+ self-loop per node), single block (unchanged).
// ---------------------------------------------------------------------------
__global__ __launch_bounds__(256) void k_csr(
    const int* __restrict__ esrc, const int* __restrict__ edst,
    int* __restrict__ coff, int* __restrict__ cslot) {
  __shared__ int cnt[Nn];
  __shared__ int offs[Nn + 1];
  __shared__ int cur[Nn];
  int tid = threadIdx.x;
  for (int n = tid; n < Nn; n += 256) cnt[n] = 0;
  __syncthreads();
  for (int e = tid; e < Ee; e += 256) atomicAdd(&cnt[edst[e]], 1);
  __syncthreads();
  if (tid == 0) {
    int run = 0;
    for (int n = 0; n < Nn; ++n) { offs[n] = run; run += cnt[n] + 1; }
    offs[Nn] = run;
  }
  __syncthreads();
  for (int n = tid; n < Nn; n += 256) cur[n] = offs[n];
  for (int n = tid; n <= Nn; n += 256) coff[n] = offs[n];
  __syncthreads();
  for (int e = tid; e < Ee; e += 256) {
    int d = edst[e];
    cslot[atomicAdd(&cur[d], 1)] = esrc[e];
  }
  for (int n = tid; n < Nn; n += 256) cslot[atomicAdd(&cur[n], 1)] = n;
}

// ---------------------------------------------------------------------------
// k_gemm1: 32 rows/block, weight-stationary (wave w owns tiles {w,w+4}).
// ---------------------------------------------------------------------------
__global__ __launch_bounds__(256, 6) void k_gemm1(
    const float* __restrict__ stt, const float* __restrict__ inp,
    const u16* __restrict__ wgh, const u16* __restrict__ wgl,
    const float* __restrict__ att_s, const float* __restrict__ att_d,
    float* __restrict__ h, float* __restrict__ asrc, float* __restrict__ adst) {
  __shared__ u16 ahL[32 * AS];
  __shared__ u16 alL[32 * AS];
  __shared__ float sredA[32], sredD[32];
  int tid = threadIdx.x;
  int m0 = blockIdx.x * 32;
  if (tid < 32) sredA[tid] = 0.f;
  else if (tid < 64) sredD[tid - 32] = 0.f;
  for (int j = tid; j < 32 * 32; j += 256) {
    int r = j >> 5, g = j & 31;
    float4 v = (g < 25) ? *(const float4*)(stt + (size_t)(m0 + r) * Uu + g * 4)
                        : *(const float4*)(inp + (size_t)(m0 + r) * Ff + (g - 25) * 4);
    ushort4 hh, ll;
    split4(v, hh, ll);
    *(ushort4*)(ahL + r * AS + g * 4) = hh;
    *(ushort4*)(alL + r * AS + g * 4) = ll;
  }
  __syncthreads();

  int w = tid >> 6, l = tid & 63, l15 = l & 15, q = l >> 4;
  int T0 = w, T1 = w + 4;
  bf16x8 w0h[4], w0l[4], w1h[4], w1l[4];
#pragma unroll
  for (int s = 0; s < 4; ++s) {
    const int o0 = (T0 * 16 + l15) * Kk + s * 32 + q * 8;
    const int o1 = (T1 * 16 + l15) * Kk + s * 32 + q * 8;
    w0h[s] = *(const bf16x8*)(wgh + o0);
    w0l[s] = *(const bf16x8*)(wgl + o0);
    w1h[s] = *(const bf16x8*)(wgh + o1);
    w1l[s] = *(const bf16x8*)(wgl + o1);
  }
  f32x4 zero = {0.f, 0.f, 0.f, 0.f};
  f32x4 acc0[2], acc1[2];
#pragma unroll
  for (int rt = 0; rt < 2; ++rt) { acc0[rt] = zero; acc1[rt] = zero; }
#pragma unroll
  for (int rt = 0; rt < 2; ++rt) {
#pragma unroll
    for (int s = 0; s < 4; ++s) {
      bf16x8 a = *(const bf16x8*)(ahL + (rt * 16 + l15) * AS + s * 32 + q * 8);
      bf16x8 b = *(const bf16x8*)(alL + (rt * 16 + l15) * AS + s * 32 + q * 8);
      acc0[rt] = __builtin_amdgcn_mfma_f32_16x16x32_bf16(a, w0h[s], acc0[rt], 0, 0, 0);
      acc1[rt] = __builtin_amdgcn_mfma_f32_16x16x32_bf16(a, w1h[s], acc1[rt], 0, 0, 0);
      acc0[rt] = __builtin_amdgcn_mfma_f32_16x16x32_bf16(b, w0h[s], acc0[rt], 0, 0, 0);
      acc1[rt] = __builtin_amdgcn_mfma_f32_16x16x32_bf16(b, w1h[s], acc1[rt], 0, 0, 0);
      acc0[rt] = __builtin_amdgcn_mfma_f32_16x16x32_bf16(a, w0l[s], acc0[rt], 0, 0, 0);
      acc1[rt] = __builtin_amdgcn_mfma_f32_16x16x32_bf16(a, w1l[s], acc1[rt], 0, 0, 0);
    }
  }

  int c0 = T0 * 16 + l15, c1 = T1 * 16 + l15;
  float av0 = (c0 < Uu) ? att_s[c0] : 0.f, dv0 = (c0 < Uu) ? att_d[c0] : 0.f;
  float av1 = (c1 < Uu) ? att_s[c1] : 0.f, dv1 = (c1 < Uu) ? att_d[c1] : 0.f;
#pragma unroll
  for (int rt = 0; rt < 2; ++rt) {
#pragma unroll
    for (int i = 0; i < 4; ++i) {
      float v0 = acc0[rt][i], v1 = acc1[rt][i];
      int row = rt * 16 + q * 4 + i;
      size_t m = (size_t)(m0 + row);
      if (c0 < Uu) h[m * Uu + c0] = v0;
      if (c1 < Uu) h[m * Uu + c1] = v1;
      float va = v0 * av0 + v1 * av1, vd = v0 * dv0 + v1 * dv1;
#pragma unroll
      for (int msk = 1; msk < 16; msk <<= 1) {
        va += __shfl_xor(va, msk, 64);
        vd += __shfl_xor(vd, msk, 64);
      }
      if (l15 == 0) {
        atomicAdd(&sredA[row], va);
        atomicAdd(&sredD[row], vd);
      }
    }
  }
  __syncthreads();
  if (tid < 32) {
    asrc[m0 + tid] = sredA[tid];
    adst[m0 + tid] = sredD[tid];
  }
}

// ---------------------------------------------------------------------------
// k_attn: one WAVE per (sample, dst). Unchanged (passing).
// ---------------------------------------------------------------------------
__global__ __launch_bounds__(256) void k_attn(
    const int* __restrict__ coff, const int* __restrict__ cslot,
    const float* __restrict__ asrc, const float* __restrict__ adst,
    const float* __restrict__ h, const float* __restrict__ gbias, const float* __restrict__ b1,
    float* __restrict__ gsf) {
  int b = blockIdx.x;
  int w = threadIdx.x >> 6, lane = threadIdx.x & 63;
  int n = blockIdx.y * 4 + w;
  int o0 = coff[n], deg = coff[n + 1] - o0;
  float ad = adst[b * Nn + n];
  const float* hb = h + (size_t)b * Nn * Uu;
  int half = lane >> 5, ll = lane & 31;
  bool act = (ll < 25);

  float ax = 0.f, ay = 0.f, az = 0.f, aw = 0.f;
  float den = 0.f;
  for (int c0 = 0; c0 < deg; c0 += 64) {
    int e = c0 + lane;
    float we = 0.f; int s = 0;
    if (e < deg) {
      s = cslot[o0 + e];
      float sc = asrc[b * Nn + s] + ad;
      sc = (sc > 0.f) ? sc : 0.2f * sc;
      we = __expf(sc);
    }
    float d = we;
#pragma unroll
    for (int msk = 1; msk < 64; msk <<= 1) d += __shfl_xor(d, msk, 64);
    den += d;

    int cn = (deg - c0 < 64) ? (deg - c0) : 64;
    for (int e2 = 0; e2 < cn; e2 += 2) {
      int eh = e2 + half;
      float w2 = __shfl(we, eh, 64);
      int s2 = __shfl(s, eh, 64);
      if (act && eh < cn) {
        const float4 hv = *(const float4*)(hb + (size_t)s2 * Uu + ll * 4);
        ax += w2 * hv.x; ay += w2 * hv.y; az += w2 * hv.z; aw += w2 * hv.w;
      }
    }
  }
  ax += __shfl_xor(ax, 32, 64);
  ay += __shfl_xor(ay, 32, 64);
  az += __shfl_xor(az, 32, 64);
  aw += __shfl_xor(aw, 32, 64);
  if (lane < 25) {
    float inv = 1.f / den;
    int u0 = lane * 4;
    float4 o;
    o.x = ax * inv + gbias[u0 + 0] + b1[u0 + 0];
    o.y = ay * inv + gbias[u0 + 1] + b1[u0 + 1];
    o.z = az * inv + gbias[u0 + 2] + b1[u0 + 2];
    o.w = aw * inv + gbias[u0 + 3] + b1[u0 + 3];
    *(float4*)(gsf + ((size_t)b * Nn + n) * Uu + u0) = o;
  }
}

// ---------------------------------------------------------------------------
// k_gru (fused ru + c), 32 rows/block. st (=gsf) for r*st AND the blend is
// preloaded once into registers via coalesced global loads (phase-2 columns
// == phase-1 pass-0 columns), eliminating all scalar LDS st reads.
// ---------------------------------------------------------------------------
__global__ __launch_bounds__(256, 5) void k_gru(
    const float* __restrict__ gsf, const float* __restrict__ inp,
    const u16* __restrict__ wruh, const u16* __restrict__ wrul,
    const float* __restrict__ bru,
    const u16* __restrict__ wch, const u16* __restrict__ wcl,
    const float* __restrict__ bc,
    float* __restrict__ out) {
  __shared__ u16 ahL[32 * AS];
  __shared__ u16 alL[32 * AS];
  __shared__ u16 ugQ[32 * Uu];     // u-gate, 16-bit fixed point
  int tid = threadIdx.x;
  int m0 = blockIdx.x * 32;
  for (int j = tid; j < 32 * 32; j += 256) {
    int r = j >> 5, g = j & 31;
    float4 v = (g < 25) ? *(const float4*)(gsf + (size_t)(m0 + r) * Uu + g * 4)
                        : *(const float4*)(inp + (size_t)(m0 + r) * Ff + (g - 25) * 4);
    ushort4 hh, ll;
    split4(v, hh, ll);
    *(ushort4*)(ahL + r * AS + g * 4) = hh;
    *(ushort4*)(alL + r * AS + g * 4) = ll;
  }

  int w = tid >> 6, l = tid & 63, l15 = l & 15, q = l >> 4;
  int c0p = w * 16 + l15, c1p = (w + 4) * 16 + l15;   // phase-2 / pass-0 cols

  // st preload (independent of LDS; overlaps staging)
  float sv[2][2][4];
#pragma unroll
  for (int rt = 0; rt < 2; ++rt) {
#pragma unroll
    for (int i = 0; i < 4; ++i) {
      int row = rt * 16 + q * 4 + i;
#pragma unroll
      for (int t = 0; t < 2; ++t) {
        int c = t ? c1p : c0p;
        sv[t][rt][i] = (c < Uu) ? gsf[(size_t)(m0 + row) * Uu + c] : 0.f;
      }
    }
  }
  __syncthreads();

  f32x4 zero = {0.f, 0.f, 0.f, 0.f};
  float pr[2][2][4];               // r*st for pass-0 cols (<100)

  // ---- phase 1: ru ----
#pragma unroll
  for (int pass = 0; pass < 2; ++pass) {
    int T0 = pass * 8 + w, T1 = T0 + 4;
    bf16x8 w0h[4], w0l[4], w1h[4], w1l[4];
#pragma unroll
    for (int s = 0; s < 4; ++s) {
      const int o0 = (T0 * 16 + l15) * Kk + s * 32 + q * 8;
      const int o1 = (T1 * 16 + l15) * Kk + s * 32 + q * 8;
      w0h[s] = *(const bf16x8*)(wruh + o0);
      w0l[s] = *(const bf16x8*)(wrul + o0);
      w1h[s] = *(const bf16x8*)(wruh + o1);
      w1l[s] = *(const bf16x8*)(wrul + o1);
    }
    f32x4 acc0[2], acc1[2];
#pragma unroll
    for (int rt = 0; rt < 2; ++rt) { acc0[rt] = zero; acc1[rt] = zero; }
#pragma unroll
    for (int rt = 0; rt < 2; ++rt) {
#pragma unroll
      for (int s = 0; s < 4; ++s) {
        bf16x8 a = *(const bf16x8*)(ahL + (rt * 16 + l15) * AS + s * 32 + q * 8);
        bf16x8 b = *(const bf16x8*)(alL + (rt * 16 + l15) * AS + s * 32 + q * 8);
        acc0[rt] = __builtin_amdgcn_mfma_f32_16x16x32_bf16(a, w0h[s], acc0[rt], 0, 0, 0);
        acc1[rt] = __builtin_amdgcn_mfma_f32_16x16x32_bf16(a, w1h[s], acc1[rt], 0, 0, 0);
        acc0[rt] = __builtin_amdgcn_mfma_f32_16x16x32_bf16(b, w0h[s], acc0[rt], 0, 0, 0);
        acc1[rt] = __builtin_amdgcn_mfma_f32_16x16x32_bf16(b, w1h[s], acc1[rt], 0, 0, 0);
        acc0[rt] = __builtin_amdgcn_mfma_f32_16x16x32_bf16(a, w0l[s], acc0[rt], 0, 0, 0);
        acc1[rt] = __builtin_amdgcn_mfma_f32_16x16x32_bf16(a, w1l[s], acc1[rt], 0, 0, 0);
      }
    }
    int c0 = T0 * 16 + l15, c1 = T1 * 16 + l15;
    float bv0 = (c0 < 2 * Uu) ? bru[c0] : 0.f;
    float bv1 = (c1 < 2 * Uu) ? bru[c1] : 0.f;
#pragma unroll
    for (int rt = 0; rt < 2; ++rt) {
#pragma unroll
      for (int i = 0; i < 4; ++i) {
        int row = rt * 16 + q * 4 + i;
#pragma unroll
        for (int t = 0; t < 2; ++t) {
          int c = t ? c1 : c0;
          float y = (t ? acc1[rt][i] : acc0[rt][i]) + (t ? bv1 : bv0);
          float g = 1.f / (1.f + __expf(-y));
          if (c < Uu) {
            pr[t][rt][i] = g * sv[t][rt][i];           // pass 0 only (c<100)
          } else if (c < 2 * Uu) {
            ugQ[row * Uu + (c - Uu)] = (u16)(g * 65535.f + 0.5f);
          }
        }
      }
    }
  }

  __syncthreads();   // all phase-1 LDS reads + ugQ writes complete
#pragma unroll
  for (int rt = 0; rt < 2; ++rt) {
#pragma unroll
    for (int i = 0; i < 4; ++i) {
      int row = rt * 16 + q * 4 + i;
#pragma unroll
      for (int t = 0; t < 2; ++t) {
        int c = t ? c1p : c0p;
        if (c < Uu) {
          float p = pr[t][rt][i];
          u16 hh = f2bf(p);
          ahL[row * AS + c] = hh;
          alL[row * AS + c] = f2bf(p - bf2f(hh));
        }
      }
    }
  }
  __syncthreads();   // cat2 = [r*st | xi] (split) ready in LDS

  // ---- phase 2: c GEMM + blend ----
  {
    int T0 = w, T1 = w + 4;
    bf16x8 w0h[4], w0l[4], w1h[4], w1l[4];
#pragma unroll
    for (int s = 0; s < 4; ++s) {
      const int o0 = (T0 * 16 + l15) * Kk + s * 32 + q * 8;
      const int o1 = (T1 * 16 + l15) * Kk + s * 32 + q * 8;
      w0h[s] = *(const bf16x8*)(wch + o0);
      w0l[s] = *(const bf16x8*)(wcl + o0);
      w1h[s] = *(const bf16x8*)(wch + o1);
      w1l[s] = *(const bf16x8*)(wcl + o1);
    }
    f32x4 acc0[2], acc1[2];
#pragma unroll
    for (int rt = 0; rt < 2; ++rt) { acc0[rt] = zero; acc1[rt] = zero; }
#pragma unroll
    for (int rt = 0; rt < 2; ++rt) {
#pragma unroll
      for (int s = 0; s < 4; ++s) {
        bf16x8 a = *(const bf16x8*)(ahL + (rt * 16 + l15) * AS + s * 32 + q * 8);
        bf16x8 b = *(const bf16x8*)(alL + (rt * 16 + l15) * AS + s * 32 + q * 8);
        acc0[rt] = __builtin_amdgcn_mfma_f32_16x16x32_bf16(a, w0h[s], acc0[rt], 0, 0, 0);
        acc1[rt] = __builtin_amdgcn_mfma_f32_16x16x32_bf16(a, w1h[s], acc1[rt], 0, 0, 0);
        acc0[rt] = __builtin_amdgcn_mfma_f32_16x16x32_bf16(b, w0h[s], acc0[rt], 0, 0, 0);
        acc1[rt] = __builtin_amdgcn_mfma_f32_16x16x32_bf16(b, w1h[s], acc1[rt], 0, 0, 0);
        acc0[rt] = __builtin_amdgcn_mfma_f32_16x16x32_bf16(a, w0l[s], acc0[rt], 0, 0, 0);
        acc1[rt] = __builtin_amdgcn_mfma_f32_16x16x32_bf16(a, w1l[s], acc1[rt], 0, 0, 0);
      }
    }
    float bv0 = (c0p < Uu) ? bc[c0p] : 0.f;
    float bv1 = (c1p < Uu) ? bc[c1p] : 0.f;
#pragma unroll
    for (int rt = 0; rt < 2; ++rt) {
#pragma unroll
      for (int i = 0; i < 4; ++i) {
        int row = rt * 16 + q * 4 + i;
        size_t m = (size_t)(m0 + row);
#pragma unroll
        for (int t = 0; t < 2; ++t) {
          int c = t ? c1p : c0p;
          if (c < Uu) {
            float y = (t ? acc1[rt][i] : acc0[rt][i]) + (t ? bv1 : bv0);
            float cv = 1.f - 2.f / (__expf(2.f * y) + 1.f);
            float u = (float)ugQ[row * Uu + c] * (1.f / 65535.f);
            out[m * Uu + c] = u * sv[t][rt][i] + (1.f - u) * cv;
          }
        }
      }
    }
  }
}

// ---------------------------------------------------------------------------
extern "C" void kernel_launch(void* const* d_in, const int* in_sizes, int n_in,
                              void* d_out, int out_size, void* d_ws, size_t ws_size,
                              hipStream_t stream) {
  const float* inp   = (const float*)d_in[0];
  const float* stt   = (const float*)d_in[1];
  const int*   esrc  = (const int*)d_in[2];
  const int*   edst  = (const int*)d_in[3];
  const float* Wg    = (const float*)d_in[4];
  const float* att_s = (const float*)d_in[5];
  const float* att_d = (const float*)d_in[6];
  const float* gbias = (const float*)d_in[7];
  const float* b1    = (const float*)d_in[8];
  const float* Wru   = (const float*)d_in[9];
  const float* bru   = (const float*)d_in[10];
  const float* Wc    = (const float*)d_in[11];
  const float* bc    = (const float*)d_in[12];
  float* out = (float*)d_out;

  char* base = (char*)d_ws;
  size_t o = 0;
  auto alloc = [&](size_t bytes) -> void* {
    void* p = base + o;
    o = (o + bytes + 255) & ~(size_t)255;
    return p;
  };
  u16* wgh  = (u16*)alloc(128 * Kk * sizeof(u16));
  u16* wgl  = (u16*)alloc(128 * Kk * sizeof(u16));
  u16* wruh = (u16*)alloc(256 * Kk * sizeof(u16));
  u16* wrul = (u16*)alloc(256 * Kk * sizeof(u16));
  u16* wch  = (u16*)alloc(128 * Kk * sizeof(u16));
  u16* wcl  = (u16*)alloc(128 * Kk * sizeof(u16));
  int* coff  = (int*)alloc((Nn + 1) * sizeof(int));
  int* cslot = (int*)alloc(ET * sizeof(int));
  float* h    = (float*)alloc((size_t)Mrows * Uu * sizeof(float));
  float* asrc = (float*)alloc((size_t)Mrows * sizeof(float));
  float* adst = (float*)alloc((size_t)Mrows * sizeof(float));
  float* gsf  = (float*)alloc((size_t)Mrows * Uu * sizeof(float));
  // total ~47.6 MB — proven footprint

  k_prep<<<32, 256, 0, stream>>>(Wg, Wru, Wc, wgh, wgl, wruh, wrul, wch, wcl);
  k_csr<<<1, 256, 0, stream>>>(esrc, edst, coff, cslot);
  k_gemm1<<<Mrows / 32, 256, 0, stream>>>(stt, inp, wgh, wgl, att_s, att_d, h, asrc, adst);
  k_attn<<<dim3(Bb, 60), 256, 0, stream>>>(coff, cslot, asrc, adst, h, gbias, b1, gsf);
  k_gru<<<Mrows / 32, 256, 0, stream>>>(gsf, inp, wruh, wrul, bru, wch, wcl, bc, out);
}

// Round 8
// 266.937 us; speedup vs baseline: 1.1944x; 1.1944x over previous
//
#include <hip/hip_runtime.h>

#define Bb 256
#define Nn 240
#define Ee 4338
#define Ff 28
#define Uu 100
#define Kk 128            // U + F
#define Mrows (Bb * Nn)   // 61440
#define ET (Ee + Nn)      // edges incl self-loops
#define AS 136            // LDS A-panel row stride in u16 (272B -> <=2-way bank alias)

typedef __attribute__((ext_vector_type(8))) short bf16x8;
typedef __attribute__((ext_vector_type(4))) float f32x4;
typedef unsigned short u16;

__device__ __forceinline__ float bf2f(u16 u) {
  union { unsigned int i; float f; } v; v.i = ((unsigned int)u) << 16; return v.f;
}
__device__ __forceinline__ u16 f2bf(float f) {
  union { float ff; unsigned int i; } v; v.ff = f;
  unsigned int x = v.i;
  return (u16)((x + 0x7fffu + ((x >> 16) & 1u)) >> 16);
}
__device__ __forceinline__ void split4(const float4 v, ushort4& h, ushort4& l) {
  u16 h0 = f2bf(v.x), h1 = f2bf(v.y), h2 = f2bf(v.z), h3 = f2bf(v.w);
  h.x = h0; h.y = h1; h.z = h2; h.w = h3;
  l.x = f2bf(v.x - bf2f(h0)); l.y = f2bf(v.y - bf2f(h1));
  l.z = f2bf(v.z - bf2f(h2)); l.w = f2bf(v.w - bf2f(h3));
}

// ---------------------------------------------------------------------------
// k_prep: fp32 weights -> padded/transposed bf16 hi/lo (unchanged).
// ---------------------------------------------------------------------------
__global__ __launch_bounds__(256) void k_prep(
    const float* __restrict__ Wg, const float* __restrict__ Wru, const float* __restrict__ Wc,
    u16* __restrict__ wgh, u16* __restrict__ wgl,
    u16* __restrict__ wruh, u16* __restrict__ wrul,
    u16* __restrict__ wch, u16* __restrict__ wcl) {
  int gt = blockIdx.x * 256 + threadIdx.x, GS = gridDim.x * 256;
  for (int i = gt; i < 128 * Kk; i += GS) {
    int c = i >> 7, k = i & 127;
    float v = (c < Uu) ? Wg[c * Kk + k] : 0.f;
    u16 h = f2bf(v); wgh[i] = h; wgl[i] = f2bf(v - bf2f(h));
  }
  for (int i = gt; i < 256 * Kk; i += GS) {
    int n = i >> 7, kp = i & 127;
    int k = (kp < Uu) ? (kp + Ff) : (kp - Uu);
    float v = (n < 2 * Uu) ? Wru[k * (2 * Uu) + n] : 0.f;
    u16 h = f2bf(v); wruh[i] = h; wrul[i] = f2bf(v - bf2f(h));
  }
  for (int i = gt; i < 128 * Kk; i += GS) {
    int n = i >> 7, kp = i & 127;
    int k = (kp < Uu) ? (kp + Ff) : (kp - Uu);
    float v = (n < Uu) ? Wc[k * Uu + n] : 0.f;
    u16 h = f2bf(v); wch[i] = h; wcl[i] = f2bf(v - bf2f(h));
  }
}

// ---------------------------------------------------------------------------
// k_csr: dst-grouped CSR (+ self-loop per node), single block (unchanged).
// ---------------------------------------------------------------------------
__global__ __launch_bounds__(256) void k_csr(
    const int* __restrict__ esrc, const int* __restrict__ edst,
    int* __restrict__ coff, int* __restrict__ cslot) {
  __shared__ int cnt[Nn];
  __shared__ int offs[Nn + 1];
  __shared__ int cur[Nn];
  int tid = threadIdx.x;
  for (int n = tid; n < Nn; n += 256) cnt[n] = 0;
  __syncthreads();
  for (int e = tid; e < Ee; e += 256) atomicAdd(&cnt[edst[e]], 1);
  __syncthreads();
  if (tid == 0) {
    int run = 0;
    for (int n = 0; n < Nn; ++n) { offs[n] = run; run += cnt[n] + 1; }
    offs[Nn] = run;
  }
  __syncthreads();
  for (int n = tid; n < Nn; n += 256) cur[n] = offs[n];
  for (int n = tid; n <= Nn; n += 256) coff[n] = offs[n];
  __syncthreads();
  for (int e = tid; e < Ee; e += 256) {
    int d = edst[e];
    cslot[atomicAdd(&cur[d], 1)] = esrc[e];
  }
  for (int n = tid; n < Nn; n += 256) cslot[atomicAdd(&cur[n], 1)] = n;
}

// ---------------------------------------------------------------------------
// k_gemm1: 32 rows/block, weight-stationary. min-waves 4 (VGPR cap 128 — no
// spill; (256,6) in r7 capped at ~85 and spilled to scratch).
// ---------------------------------------------------------------------------
__global__ __launch_bounds__(256, 4) void k_gemm1(
    const float* __restrict__ stt, const float* __restrict__ inp,
    const u16* __restrict__ wgh, const u16* __restrict__ wgl,
    const float* __restrict__ att_s, const float* __restrict__ att_d,
    float* __restrict__ h, float* __restrict__ asrc, float* __restrict__ adst) {
  __shared__ u16 ahL[32 * AS];
  __shared__ u16 alL[32 * AS];
  __shared__ float sredA[32], sredD[32];
  int tid = threadIdx.x;
  int m0 = blockIdx.x * 32;
  if (tid < 32) sredA[tid] = 0.f;
  else if (tid < 64) sredD[tid - 32] = 0.f;
  for (int j = tid; j < 32 * 32; j += 256) {
    int r = j >> 5, g = j & 31;
    float4 v = (g < 25) ? *(const float4*)(stt + (size_t)(m0 + r) * Uu + g * 4)
                        : *(const float4*)(inp + (size_t)(m0 + r) * Ff + (g - 25) * 4);
    ushort4 hh, ll;
    split4(v, hh, ll);
    *(ushort4*)(ahL + r * AS + g * 4) = hh;
    *(ushort4*)(alL + r * AS + g * 4) = ll;
  }
  __syncthreads();

  int w = tid >> 6, l = tid & 63, l15 = l & 15, q = l >> 4;
  int T0 = w, T1 = w + 4;
  bf16x8 w0h[4], w0l[4], w1h[4], w1l[4];
#pragma unroll
  for (int s = 0; s < 4; ++s) {
    const int o0 = (T0 * 16 + l15) * Kk + s * 32 + q * 8;
    const int o1 = (T1 * 16 + l15) * Kk + s * 32 + q * 8;
    w0h[s] = *(const bf16x8*)(wgh + o0);
    w0l[s] = *(const bf16x8*)(wgl + o0);
    w1h[s] = *(const bf16x8*)(wgh + o1);
    w1l[s] = *(const bf16x8*)(wgl + o1);
  }
  f32x4 zero = {0.f, 0.f, 0.f, 0.f};
  f32x4 acc0[2], acc1[2];
#pragma unroll
  for (int rt = 0; rt < 2; ++rt) { acc0[rt] = zero; acc1[rt] = zero; }
#pragma unroll
  for (int rt = 0; rt < 2; ++rt) {
#pragma unroll
    for (int s = 0; s < 4; ++s) {
      bf16x8 a = *(const bf16x8*)(ahL + (rt * 16 + l15) * AS + s * 32 + q * 8);
      bf16x8 b = *(const bf16x8*)(alL + (rt * 16 + l15) * AS + s * 32 + q * 8);
      acc0[rt] = __builtin_amdgcn_mfma_f32_16x16x32_bf16(a, w0h[s], acc0[rt], 0, 0, 0);
      acc1[rt] = __builtin_amdgcn_mfma_f32_16x16x32_bf16(a, w1h[s], acc1[rt], 0, 0, 0);
      acc0[rt] = __builtin_amdgcn_mfma_f32_16x16x32_bf16(b, w0h[s], acc0[rt], 0, 0, 0);
      acc1[rt] = __builtin_amdgcn_mfma_f32_16x16x32_bf16(b, w1h[s], acc1[rt], 0, 0, 0);
      acc0[rt] = __builtin_amdgcn_mfma_f32_16x16x32_bf16(a, w0l[s], acc0[rt], 0, 0, 0);
      acc1[rt] = __builtin_amdgcn_mfma_f32_16x16x32_bf16(a, w1l[s], acc1[rt], 0, 0, 0);
    }
  }

  int c0 = T0 * 16 + l15, c1 = T1 * 16 + l15;
  float av0 = (c0 < Uu) ? att_s[c0] : 0.f, dv0 = (c0 < Uu) ? att_d[c0] : 0.f;
  float av1 = (c1 < Uu) ? att_s[c1] : 0.f, dv1 = (c1 < Uu) ? att_d[c1] : 0.f;
#pragma unroll
  for (int rt = 0; rt < 2; ++rt) {
#pragma unroll
    for (int i = 0; i < 4; ++i) {
      float v0 = acc0[rt][i], v1 = acc1[rt][i];
      int row = rt * 16 + q * 4 + i;
      size_t m = (size_t)(m0 + row);
      if (c0 < Uu) h[m * Uu + c0] = v0;
      if (c1 < Uu) h[m * Uu + c1] = v1;
      float va = v0 * av0 + v1 * av1, vd = v0 * dv0 + v1 * dv1;
#pragma unroll
      for (int msk = 1; msk < 16; msk <<= 1) {
        va += __shfl_xor(va, msk, 64);
        vd += __shfl_xor(vd, msk, 64);
      }
      if (l15 == 0) {
        atomicAdd(&sredA[row], va);
        atomicAdd(&sredD[row], vd);
      }
    }
  }
  __syncthreads();
  if (tid < 32) {
    asrc[m0 + tid] = sredA[tid];
    adst[m0 + tid] = sredD[tid];
  }
}

// ---------------------------------------------------------------------------
// k_attn: one WAVE per (sample, dst). Unchanged (passing).
// ---------------------------------------------------------------------------
__global__ __launch_bounds__(256) void k_attn(
    const int* __restrict__ coff, const int* __restrict__ cslot,
    const float* __restrict__ asrc, const float* __restrict__ adst,
    const float* __restrict__ h, const float* __restrict__ gbias, const float* __restrict__ b1,
    float* __restrict__ gsf) {
  int b = blockIdx.x;
  int w = threadIdx.x >> 6, lane = threadIdx.x & 63;
  int n = blockIdx.y * 4 + w;
  int o0 = coff[n], deg = coff[n + 1] - o0;
  float ad = adst[b * Nn + n];
  const float* hb = h + (size_t)b * Nn * Uu;
  int half = lane >> 5, ll = lane & 31;
  bool act = (ll < 25);

  float ax = 0.f, ay = 0.f, az = 0.f, aw = 0.f;
  float den = 0.f;
  for (int c0 = 0; c0 < deg; c0 += 64) {
    int e = c0 + lane;
    float we = 0.f; int s = 0;
    if (e < deg) {
      s = cslot[o0 + e];
      float sc = asrc[b * Nn + s] + ad;
      sc = (sc > 0.f) ? sc : 0.2f * sc;
      we = __expf(sc);
    }
    float d = we;
#pragma unroll
    for (int msk = 1; msk < 64; msk <<= 1) d += __shfl_xor(d, msk, 64);
    den += d;

    int cn = (deg - c0 < 64) ? (deg - c0) : 64;
    for (int e2 = 0; e2 < cn; e2 += 2) {
      int eh = e2 + half;
      float w2 = __shfl(we, eh, 64);
      int s2 = __shfl(s, eh, 64);
      if (act && eh < cn) {
        const float4 hv = *(const float4*)(hb + (size_t)s2 * Uu + ll * 4);
        ax += w2 * hv.x; ay += w2 * hv.y; az += w2 * hv.z; aw += w2 * hv.w;
      }
    }
  }
  ax += __shfl_xor(ax, 32, 64);
  ay += __shfl_xor(ay, 32, 64);
  az += __shfl_xor(az, 32, 64);
  aw += __shfl_xor(aw, 32, 64);
  if (lane < 25) {
    float inv = 1.f / den;
    int u0 = lane * 4;
    float4 o;
    o.x = ax * inv + gbias[u0 + 0] + b1[u0 + 0];
    o.y = ay * inv + gbias[u0 + 1] + b1[u0 + 1];
    o.z = az * inv + gbias[u0 + 2] + b1[u0 + 2];
    o.w = aw * inv + gbias[u0 + 3] + b1[u0 + 3];
    *(float4*)(gsf + ((size_t)b * Nn + n) * Uu + u0) = o;
  }
}

// ---------------------------------------------------------------------------
// k_gru (fused ru + c), 32 rows/block, register st-preload. min-waves 4:
// (256,5) in r7 forced VGPR=48 -> scratch spill (+200MB HBM). 128-cap fits
// the ~110-reg live set.
// ---------------------------------------------------------------------------
__global__ __launch_bounds__(256, 4) void k_gru(
    const float* __restrict__ gsf, const float* __restrict__ inp,
    const u16* __restrict__ wruh, const u16* __restrict__ wrul,
    const float* __restrict__ bru,
    const u16* __restrict__ wch, const u16* __restrict__ wcl,
    const float* __restrict__ bc,
    float* __restrict__ out) {
  __shared__ u16 ahL[32 * AS];
  __shared__ u16 alL[32 * AS];
  __shared__ u16 ugQ[32 * Uu];     // u-gate, 16-bit fixed point
  int tid = threadIdx.x;
  int m0 = blockIdx.x * 32;
  for (int j = tid; j < 32 * 32; j += 256) {
    int r = j >> 5, g = j & 31;
    float4 v = (g < 25) ? *(const float4*)(gsf + (size_t)(m0 + r) * Uu + g * 4)
                        : *(const float4*)(inp + (size_t)(m0 + r) * Ff + (g - 25) * 4);
    ushort4 hh, ll;
    split4(v, hh, ll);
    *(ushort4*)(ahL + r * AS + g * 4) = hh;
    *(ushort4*)(alL + r * AS + g * 4) = ll;
  }

  int w = tid >> 6, l = tid & 63, l15 = l & 15, q = l >> 4;
  int c0p = w * 16 + l15, c1p = (w + 4) * 16 + l15;   // phase-2 / pass-0 cols

  // st preload (independent of LDS; overlaps staging)
  float sv[2][2][4];
#pragma unroll
  for (int rt = 0; rt < 2; ++rt) {
#pragma unroll
    for (int i = 0; i < 4; ++i) {
      int row = rt * 16 + q * 4 + i;
#pragma unroll
      for (int t = 0; t < 2; ++t) {
        int c = t ? c1p : c0p;
        sv[t][rt][i] = (c < Uu) ? gsf[(size_t)(m0 + row) * Uu + c] : 0.f;
      }
    }
  }
  __syncthreads();

  f32x4 zero = {0.f, 0.f, 0.f, 0.f};
  float pr[2][2][4];               // r*st for pass-0 cols (<100)

  // ---- phase 1: ru ----
#pragma unroll
  for (int pass = 0; pass < 2; ++pass) {
    int T0 = pass * 8 + w, T1 = T0 + 4;
    bf16x8 w0h[4], w0l[4], w1h[4], w1l[4];
#pragma unroll
    for (int s = 0; s < 4; ++s) {
      const int o0 = (T0 * 16 + l15) * Kk + s * 32 + q * 8;
      const int o1 = (T1 * 16 + l15) * Kk + s * 32 + q * 8;
      w0h[s] = *(const bf16x8*)(wruh + o0);
      w0l[s] = *(const bf16x8*)(wrul + o0);
      w1h[s] = *(const bf16x8*)(wruh + o1);
      w1l[s] = *(const bf16x8*)(wrul + o1);
    }
    f32x4 acc0[2], acc1[2];
#pragma unroll
    for (int rt = 0; rt < 2; ++rt) { acc0[rt] = zero; acc1[rt] = zero; }
#pragma unroll
    for (int rt = 0; rt < 2; ++rt) {
#pragma unroll
      for (int s = 0; s < 4; ++s) {
        bf16x8 a = *(const bf16x8*)(ahL + (rt * 16 + l15) * AS + s * 32 + q * 8);
        bf16x8 b = *(const bf16x8*)(alL + (rt * 16 + l15) * AS + s * 32 + q * 8);
        acc0[rt] = __builtin_amdgcn_mfma_f32_16x16x32_bf16(a, w0h[s], acc0[rt], 0, 0, 0);
        acc1[rt] = __builtin_amdgcn_mfma_f32_16x16x32_bf16(a, w1h[s], acc1[rt], 0, 0, 0);
        acc0[rt] = __builtin_amdgcn_mfma_f32_16x16x32_bf16(b, w0h[s], acc0[rt], 0, 0, 0);
        acc1[rt] = __builtin_amdgcn_mfma_f32_16x16x32_bf16(b, w1h[s], acc1[rt], 0, 0, 0);
        acc0[rt] = __builtin_amdgcn_mfma_f32_16x16x32_bf16(a, w0l[s], acc0[rt], 0, 0, 0);
        acc1[rt] = __builtin_amdgcn_mfma_f32_16x16x32_bf16(a, w1l[s], acc1[rt], 0, 0, 0);
      }
    }
    int c0 = T0 * 16 + l15, c1 = T1 * 16 + l15;
    float bv0 = (c0 < 2 * Uu) ? bru[c0] : 0.f;
    float bv1 = (c1 < 2 * Uu) ? bru[c1] : 0.f;
#pragma unroll
    for (int rt = 0; rt < 2; ++rt) {
#pragma unroll
      for (int i = 0; i < 4; ++i) {
        int row = rt * 16 + q * 4 + i;
#pragma unroll
        for (int t = 0; t < 2; ++t) {
          int c = t ? c1 : c0;
          float y = (t ? acc1[rt][i] : acc0[rt][i]) + (t ? bv1 : bv0);
          float g = 1.f / (1.f + __expf(-y));
          if (c < Uu) {
            pr[t][rt][i] = g * sv[t][rt][i];           // pass 0 only (c<100)
          } else if (c < 2 * Uu) {
            ugQ[row * Uu + (c - Uu)] = (u16)(g * 65535.f + 0.5f);
          }
        }
      }
    }
  }

  __syncthreads();   // all phase-1 LDS reads + ugQ writes complete
#pragma unroll
  for (int rt = 0; rt < 2; ++rt) {
#pragma unroll
    for (int i = 0; i < 4; ++i) {
      int row = rt * 16 + q * 4 + i;
#pragma unroll
      for (int t = 0; t < 2; ++t) {
        int c = t ? c1p : c0p;
        if (c < Uu) {
          float p = pr[t][rt][i];
          u16 hh = f2bf(p);
          ahL[row * AS + c] = hh;
          alL[row * AS + c] = f2bf(p - bf2f(hh));
        }
      }
    }
  }
  __syncthreads();   // cat2 = [r*st | xi] (split) ready in LDS

  // ---- phase 2: c GEMM + blend ----
  {
    int T0 = w, T1 = w + 4;
    bf16x8 w0h[4], w0l[4], w1h[4], w1l[4];
#pragma unroll
    for (int s = 0; s < 4; ++s) {
      const int o0 = (T0 * 16 + l15) * Kk + s * 32 + q * 8;
      const int o1 = (T1 * 16 + l15) * Kk + s * 32 + q * 8;
      w0h[s] = *(const bf16x8*)(wch + o0);
      w0l[s] = *(const bf16x8*)(wcl + o0);
      w1h[s] = *(const bf16x8*)(wch + o1);
      w1l[s] = *(const bf16x8*)(wcl + o1);
    }
    f32x4 acc0[2], acc1[2];
#pragma unroll
    for (int rt = 0; rt < 2; ++rt) { acc0[rt] = zero; acc1[rt] = zero; }
#pragma unroll
    for (int rt = 0; rt < 2; ++rt) {
#pragma unroll
      for (int s = 0; s < 4; ++s) {
        bf16x8 a = *(const bf16x8*)(ahL + (rt * 16 + l15) * AS + s * 32 + q * 8);
        bf16x8 b = *(const bf16x8*)(alL + (rt * 16 + l15) * AS + s * 32 + q * 8);
        acc0[rt] = __builtin_amdgcn_mfma_f32_16x16x32_bf16(a, w0h[s], acc0[rt], 0, 0, 0);
        acc1[rt] = __builtin_amdgcn_mfma_f32_16x16x32_bf16(a, w1h[s], acc1[rt], 0, 0, 0);
        acc0[rt] = __builtin_amdgcn_mfma_f32_16x16x32_bf16(b, w0h[s], acc0[rt], 0, 0, 0);
        acc1[rt] = __builtin_amdgcn_mfma_f32_16x16x32_bf16(b, w1h[s], acc1[rt], 0, 0, 0);
        acc0[rt] = __builtin_amdgcn_mfma_f32_16x16x32_bf16(a, w0l[s], acc0[rt], 0, 0, 0);
        acc1[rt] = __builtin_amdgcn_mfma_f32_16x16x32_bf16(a, w1l[s], acc1[rt], 0, 0, 0);
      }
    }
    float bv0 = (c0p < Uu) ? bc[c0p] : 0.f;
    float bv1 = (c1p < Uu) ? bc[c1p] : 0.f;
#pragma unroll
    for (int rt = 0; rt < 2; ++rt) {
#pragma unroll
      for (int i = 0; i < 4; ++i) {
        int row = rt * 16 + q * 4 + i;
        size_t m = (size_t)(m0 + row);
#pragma unroll
        for (int t = 0; t < 2; ++t) {
          int c = t ? c1p : c0p;
          if (c < Uu) {
            float y = (t ? acc1[rt][i] : acc0[rt][i]) + (t ? bv1 : bv0);
            float cv = 1.f - 2.f / (__expf(2.f * y) + 1.f);
            float u = (float)ugQ[row * Uu + c] * (1.f / 65535.f);
            out[m * Uu + c] = u * sv[t][rt][i] + (1.f - u) * cv;
          }
        }
      }
    }
  }
}

// ---------------------------------------------------------------------------
extern "C" void kernel_launch(void* const* d_in, const int* in_sizes, int n_in,
                              void* d_out, int out_size, void* d_ws, size_t ws_size,
                              hipStream_t stream) {
  const float* inp   = (const float*)d_in[0];
  const float* stt   = (const float*)d_in[1];
  const int*   esrc  = (const int*)d_in[2];
  const int*   edst  = (const int*)d_in[3];
  const float* Wg    = (const float*)d_in[4];
  const float* att_s = (const float*)d_in[5];
  const float* att_d = (const float*)d_in[6];
  const float* gbias = (const float*)d_in[7];
  const float* b1    = (const float*)d_in[8];
  const float* Wru   = (const float*)d_in[9];
  const float* bru   = (const float*)d_in[10];
  const float* Wc    = (const float*)d_in[11];
  const float* bc    = (const float*)d_in[12];
  float* out = (float*)d_out;

  char* base = (char*)d_ws;
  size_t o = 0;
  auto alloc = [&](size_t bytes) -> void* {
    void* p = base + o;
    o = (o + bytes + 255) & ~(size_t)255;
    return p;
  };
  u16* wgh  = (u16*)alloc(128 * Kk * sizeof(u16));
  u16* wgl  = (u16*)alloc(128 * Kk * sizeof(u16));
  u16* wruh = (u16*)alloc(256 * Kk * sizeof(u16));
  u16* wrul = (u16*)alloc(256 * Kk * sizeof(u16));
  u16* wch  = (u16*)alloc(128 * Kk * sizeof(u16));
  u16* wcl  = (u16*)alloc(128 * Kk * sizeof(u16));
  int* coff  = (int*)alloc((Nn + 1) * sizeof(int));
  int* cslot = (int*)alloc(ET * sizeof(int));
  float* h    = (float*)alloc((size_t)Mrows * Uu * sizeof(float));
  float* asrc = (float*)alloc((size_t)Mrows * sizeof(float));
  float* adst = (float*)alloc((size_t)Mrows * sizeof(float));
  float* gsf  = (float*)alloc((size_t)Mrows * Uu * sizeof(float));
  // total ~47.6 MB — proven footprint

  k_prep<<<32, 256, 0, stream>>>(Wg, Wru, Wc, wgh, wgl, wruh, wrul, wch, wcl);
  k_csr<<<1, 256, 0, stream>>>(esrc, edst, coff, cslot);
  k_gemm1<<<Mrows / 32, 256, 0, stream>>>(stt, inp, wgh, wgl, att_s, att_d, h, asrc, adst);
  k_attn<<<dim3(Bb, 60), 256, 0, stream>>>(coff, cslot, asrc, adst, h, gbias, b1, gsf);
  k_gru<<<Mrows / 32, 256, 0, stream>>>(gsf, inp, wruh, wrul, bru, wch, wcl, bc, out);
}

// Round 10
// 241.815 us; speedup vs baseline: 1.3185x; 1.1039x over previous
//
#include <hip/hip_runtime.h>

#define Bb 256
#define Nn 240
#define Ee 4338
#define Ff 28
#define Uu 100
#define Kk 128            // U + F
#define Mrows (Bb * Nn)   // 61440
#define ET (Ee + Nn)      // edges incl self-loops
#define AS 136            // LDS A-panel row stride in u16 (272B -> <=2-way bank alias)

typedef __attribute__((ext_vector_type(8))) short bf16x8;
typedef __attribute__((ext_vector_type(4))) float f32x4;
typedef unsigned short u16;

__device__ __forceinline__ float bf2f(u16 u) {
  union { unsigned int i; float f; } v; v.i = ((unsigned int)u) << 16; return v.f;
}
__device__ __forceinline__ u16 f2bf(float f) {
  union { float ff; unsigned int i; } v; v.ff = f;
  unsigned int x = v.i;
  return (u16)((x + 0x7fffu + ((x >> 16) & 1u)) >> 16);
}
__device__ __forceinline__ void split4(const float4 v, ushort4& h, ushort4& l) {
  u16 h0 = f2bf(v.x), h1 = f2bf(v.y), h2 = f2bf(v.z), h3 = f2bf(v.w);
  h.x = h0; h.y = h1; h.z = h2; h.w = h3;
  l.x = f2bf(v.x - bf2f(h0)); l.y = f2bf(v.y - bf2f(h1));
  l.z = f2bf(v.z - bf2f(h2)); l.w = f2bf(v.w - bf2f(h3));
}

// ---------------------------------------------------------------------------
// k_prep: fp32 weights -> padded/transposed bf16 hi/lo (unchanged).
// ---------------------------------------------------------------------------
__global__ __launch_bounds__(256) void k_prep(
    const float* __restrict__ Wg, const float* __restrict__ Wru, const float* __restrict__ Wc,
    u16* __restrict__ wgh, u16* __restrict__ wgl,
    u16* __restrict__ wruh, u16* __restrict__ wrul,
    u16* __restrict__ wch, u16* __restrict__ wcl) {
  int gt = blockIdx.x * 256 + threadIdx.x, GS = gridDim.x * 256;
  for (int i = gt; i < 128 * Kk; i += GS) {
    int c = i >> 7, k = i & 127;
    float v = (c < Uu) ? Wg[c * Kk + k] : 0.f;
    u16 h = f2bf(v); wgh[i] = h; wgl[i] = f2bf(v - bf2f(h));
  }
  for (int i = gt; i < 256 * Kk; i += GS) {
    int n = i >> 7, kp = i & 127;
    int k = (kp < Uu) ? (kp + Ff) : (kp - Uu);
    float v = (n < 2 * Uu) ? Wru[k * (2 * Uu) + n] : 0.f;
    u16 h = f2bf(v); wruh[i] = h; wrul[i] = f2bf(v - bf2f(h));
  }
  for (int i = gt; i < 128 * Kk; i += GS) {
    int n = i >> 7, kp = i & 127;
    int k = (kp < Uu) ? (kp + Ff) : (kp - Uu);
    float v = (n < Uu) ? Wc[k * Uu + n] : 0.f;
    u16 h = f2bf(v); wch[i] = h; wcl[i] = f2bf(v - bf2f(h));
  }
}

// ---------------------------------------------------------------------------
// k_csr: dst-grouped CSR (+ self-loop per node), single block (unchanged).
// ---------------------------------------------------------------------------
__global__ __launch_bounds__(256) void k_csr(
    const int* __restrict__ esrc, const int* __restrict__ edst,
    int* __restrict__ coff, int* __restrict__ cslot) {
  __shared__ int cnt[Nn];
  __shared__ int offs[Nn + 1];
  __shared__ int cur[Nn];
  int tid = threadIdx.x;
  for (int n = tid; n < Nn; n += 256) cnt[n] = 0;
  __syncthreads();
  for (int e = tid; e < Ee; e += 256) atomicAdd(&cnt[edst[e]], 1);
  __syncthreads();
  if (tid == 0) {
    int run = 0;
    for (int n = 0; n < Nn; ++n) { offs[n] = run; run += cnt[n] + 1; }
    offs[Nn] = run;
  }
  __syncthreads();
  for (int n = tid; n < Nn; n += 256) cur[n] = offs[n];
  for (int n = tid; n <= Nn; n += 256) coff[n] = offs[n];
  __syncthreads();
  for (int e = tid; e < Ee; e += 256) {
    int d = edst[e];
    cslot[atomicAdd(&cur[d], 1)] = esrc[e];
  }
  for (int n = tid; n < Nn; n += 256) cslot[atomicAdd(&cur[n], 1)] = n;
}

// ---------------------------------------------------------------------------
// k_gemm1: 32 rows/block, ONE tile per wave per pass (2 passes).
// FIX r9: sa/sd were [4] but indexed [rt*4+i] (0..7) -> OOB/UB corrupted
// asrc/adst. Now [8].
// ---------------------------------------------------------------------------
__global__ __launch_bounds__(256, 4) void k_gemm1(
    const float* __restrict__ stt, const float* __restrict__ inp,
    const u16* __restrict__ wgh, const u16* __restrict__ wgl,
    const float* __restrict__ att_s, const float* __restrict__ att_d,
    float* __restrict__ h, float* __restrict__ asrc, float* __restrict__ adst) {
  __shared__ u16 ahL[32 * AS];
  __shared__ u16 alL[32 * AS];
  __shared__ float sredA[32], sredD[32];
  int tid = threadIdx.x;
  int m0 = blockIdx.x * 32;
  if (tid < 32) sredA[tid] = 0.f;
  else if (tid < 64) sredD[tid - 32] = 0.f;
  for (int j = tid; j < 32 * 32; j += 256) {
    int r = j >> 5, g = j & 31;
    float4 v = (g < 25) ? *(const float4*)(stt + (size_t)(m0 + r) * Uu + g * 4)
                        : *(const float4*)(inp + (size_t)(m0 + r) * Ff + (g - 25) * 4);
    ushort4 hh, ll;
    split4(v, hh, ll);
    *(ushort4*)(ahL + r * AS + g * 4) = hh;
    *(ushort4*)(alL + r * AS + g * 4) = ll;
  }
  __syncthreads();

  int w = tid >> 6, l = tid & 63, l15 = l & 15, q = l >> 4;
  f32x4 zero = {0.f, 0.f, 0.f, 0.f};
  float sa[8] = {0.f, 0.f, 0.f, 0.f, 0.f, 0.f, 0.f, 0.f};
  float sd[8] = {0.f, 0.f, 0.f, 0.f, 0.f, 0.f, 0.f, 0.f};

#pragma unroll
  for (int pass = 0; pass < 2; ++pass) {
    int T = pass * 4 + w;
    bf16x8 wh[4], wl[4];
#pragma unroll
    for (int s = 0; s < 4; ++s) {
      const int o = (T * 16 + l15) * Kk + s * 32 + q * 8;
      wh[s] = *(const bf16x8*)(wgh + o);
      wl[s] = *(const bf16x8*)(wgl + o);
    }
    f32x4 acc[2];
    acc[0] = zero; acc[1] = zero;
#pragma unroll
    for (int rt = 0; rt < 2; ++rt) {
#pragma unroll
      for (int s = 0; s < 4; ++s) {
        bf16x8 a = *(const bf16x8*)(ahL + (rt * 16 + l15) * AS + s * 32 + q * 8);
        bf16x8 b = *(const bf16x8*)(alL + (rt * 16 + l15) * AS + s * 32 + q * 8);
        acc[rt] = __builtin_amdgcn_mfma_f32_16x16x32_bf16(a, wh[s], acc[rt], 0, 0, 0);
        acc[rt] = __builtin_amdgcn_mfma_f32_16x16x32_bf16(b, wh[s], acc[rt], 0, 0, 0);
        acc[rt] = __builtin_amdgcn_mfma_f32_16x16x32_bf16(a, wl[s], acc[rt], 0, 0, 0);
      }
    }
    int c = T * 16 + l15;
    float av = (c < Uu) ? att_s[c] : 0.f, dv = (c < Uu) ? att_d[c] : 0.f;
#pragma unroll
    for (int rt = 0; rt < 2; ++rt) {
#pragma unroll
      for (int i = 0; i < 4; ++i) {
        float v = acc[rt][i];
        int row = rt * 16 + q * 4 + i;
        if (c < Uu) h[(size_t)(m0 + row) * Uu + c] = v;
        sa[rt * 4 + i] += v * av;
        sd[rt * 4 + i] += v * dv;
      }
    }
  }
  // reduce att dots across the 16 columns of each wave's tiles
#pragma unroll
  for (int rt = 0; rt < 2; ++rt) {
#pragma unroll
    for (int i = 0; i < 4; ++i) {
      float va = sa[rt * 4 + i], vd = sd[rt * 4 + i];
#pragma unroll
      for (int msk = 1; msk < 16; msk <<= 1) {
        va += __shfl_xor(va, msk, 64);
        vd += __shfl_xor(vd, msk, 64);
      }
      int row = rt * 16 + q * 4 + i;
      if (l15 == 0) {
        atomicAdd(&sredA[row], va);
        atomicAdd(&sredD[row], vd);
      }
    }
  }
  __syncthreads();
  if (tid < 32) {
    asrc[m0 + tid] = sredA[tid];
    adst[m0 + tid] = sredD[tid];
  }
}

// ---------------------------------------------------------------------------
// k_attn: one WAVE per (sample, dst). Unchanged (passing).
// ---------------------------------------------------------------------------
__global__ __launch_bounds__(256) void k_attn(
    const int* __restrict__ coff, const int* __restrict__ cslot,
    const float* __restrict__ asrc, const float* __restrict__ adst,
    const float* __restrict__ h, const float* __restrict__ gbias, const float* __restrict__ b1,
    float* __restrict__ gsf) {
  int b = blockIdx.x;
  int w = threadIdx.x >> 6, lane = threadIdx.x & 63;
  int n = blockIdx.y * 4 + w;
  int o0 = coff[n], deg = coff[n + 1] - o0;
  float ad = adst[b * Nn + n];
  const float* hb = h + (size_t)b * Nn * Uu;
  int half = lane >> 5, ll = lane & 31;
  bool act = (ll < 25);

  float ax = 0.f, ay = 0.f, az = 0.f, aw = 0.f;
  float den = 0.f;
  for (int c0 = 0; c0 < deg; c0 += 64) {
    int e = c0 + lane;
    float we = 0.f; int s = 0;
    if (e < deg) {
      s = cslot[o0 + e];
      float sc = asrc[b * Nn + s] + ad;
      sc = (sc > 0.f) ? sc : 0.2f * sc;
      we = __expf(sc);
    }
    float d = we;
#pragma unroll
    for (int msk = 1; msk < 64; msk <<= 1) d += __shfl_xor(d, msk, 64);
    den += d;

    int cn = (deg - c0 < 64) ? (deg - c0) : 64;
    for (int e2 = 0; e2 < cn; e2 += 2) {
      int eh = e2 + half;
      float w2 = __shfl(we, eh, 64);
      int s2 = __shfl(s, eh, 64);
      if (act && eh < cn) {
        const float4 hv = *(const float4*)(hb + (size_t)s2 * Uu + ll * 4);
        ax += w2 * hv.x; ay += w2 * hv.y; az += w2 * hv.z; aw += w2 * hv.w;
      }
    }
  }
  ax += __shfl_xor(ax, 32, 64);
  ay += __shfl_xor(ay, 32, 64);
  az += __shfl_xor(az, 32, 64);
  aw += __shfl_xor(aw, 32, 64);
  if (lane < 25) {
    float inv = 1.f / den;
    int u0 = lane * 4;
    float4 o;
    o.x = ax * inv + gbias[u0 + 0] + b1[u0 + 0];
    o.y = ay * inv + gbias[u0 + 1] + b1[u0 + 1];
    o.z = az * inv + gbias[u0 + 2] + b1[u0 + 2];
    o.w = aw * inv + gbias[u0 + 3] + b1[u0 + 3];
    *(float4*)(gsf + ((size_t)b * Nn + n) * Uu + u0) = o;
  }
}

// ---------------------------------------------------------------------------
// k_gru (fused ru + c), 32 rows/block, ONE tile/wave/pass: phase1 = 4 passes
// over 16 ru tiles, phase2 = 2 passes over 8 c tiles. Live regs ~100 < 128.
// Phase-1 passes 0,1 columns == phase-2 pass 0,1 columns (sv/pr alignment).
// ---------------------------------------------------------------------------
__global__ __launch_bounds__(256, 4) void k_gru(
    const float* __restrict__ gsf, const float* __restrict__ inp,
    const u16* __restrict__ wruh, const u16* __restrict__ wrul,
    const float* __restrict__ bru,
    const u16* __restrict__ wch, const u16* __restrict__ wcl,
    const float* __restrict__ bc,
    float* __restrict__ out) {
  __shared__ u16 ahL[32 * AS];
  __shared__ u16 alL[32 * AS];
  __shared__ u16 ugQ[32 * Uu];     // u-gate, 16-bit fixed point
  int tid = threadIdx.x;
  int m0 = blockIdx.x * 32;
  for (int j = tid; j < 32 * 32; j += 256) {
    int r = j >> 5, g = j & 31;
    float4 v = (g < 25) ? *(const float4*)(gsf + (size_t)(m0 + r) * Uu + g * 4)
                        : *(const float4*)(inp + (size_t)(m0 + r) * Ff + (g - 25) * 4);
    ushort4 hh, ll;
    split4(v, hh, ll);
    *(ushort4*)(ahL + r * AS + g * 4) = hh;
    *(ushort4*)(alL + r * AS + g * 4) = ll;
  }

  int w = tid >> 6, l = tid & 63, l15 = l & 15, q = l >> 4;
  int c0p = w * 16 + l15, c1p = (w + 4) * 16 + l15;   // pass-0/1 (and phase-2) cols

  // st preload (independent of LDS; overlaps staging)
  float sv[2][2][4];
#pragma unroll
  for (int rt = 0; rt < 2; ++rt) {
#pragma unroll
    for (int i = 0; i < 4; ++i) {
      int row = rt * 16 + q * 4 + i;
#pragma unroll
      for (int t = 0; t < 2; ++t) {
        int c = t ? c1p : c0p;
        sv[t][rt][i] = (c < Uu) ? gsf[(size_t)(m0 + row) * Uu + c] : 0.f;
      }
    }
  }
  __syncthreads();

  f32x4 zero = {0.f, 0.f, 0.f, 0.f};
  float pr[2][2][4];               // r*st for pass 0/1 cols (<100)

  // ---- phase 1: ru, 4 passes of 1 tile ----
#pragma unroll
  for (int pass = 0; pass < 4; ++pass) {
    int T = pass * 4 + w;
    bf16x8 wh[4], wl[4];
#pragma unroll
    for (int s = 0; s < 4; ++s) {
      const int o = (T * 16 + l15) * Kk + s * 32 + q * 8;
      wh[s] = *(const bf16x8*)(wruh + o);
      wl[s] = *(const bf16x8*)(wrul + o);
    }
    f32x4 acc[2];
    acc[0] = zero; acc[1] = zero;
#pragma unroll
    for (int rt = 0; rt < 2; ++rt) {
#pragma unroll
      for (int s = 0; s < 4; ++s) {
        bf16x8 a = *(const bf16x8*)(ahL + (rt * 16 + l15) * AS + s * 32 + q * 8);
        bf16x8 b = *(const bf16x8*)(alL + (rt * 16 + l15) * AS + s * 32 + q * 8);
        acc[rt] = __builtin_amdgcn_mfma_f32_16x16x32_bf16(a, wh[s], acc[rt], 0, 0, 0);
        acc[rt] = __builtin_amdgcn_mfma_f32_16x16x32_bf16(b, wh[s], acc[rt], 0, 0, 0);
        acc[rt] = __builtin_amdgcn_mfma_f32_16x16x32_bf16(a, wl[s], acc[rt], 0, 0, 0);
      }
    }
    int c = T * 16 + l15;
    float bv = (c < 2 * Uu) ? bru[c] : 0.f;
#pragma unroll
    for (int rt = 0; rt < 2; ++rt) {
#pragma unroll
      for (int i = 0; i < 4; ++i) {
        int row = rt * 16 + q * 4 + i;
        float y = acc[rt][i] + bv;
        float g = 1.f / (1.f + __expf(-y));
        if (pass < 2) {
          if (c < Uu) pr[pass][rt][i] = g * sv[pass][rt][i];
        }
        if (c >= Uu && c < 2 * Uu) {
          ugQ[row * Uu + (c - Uu)] = (u16)(g * 65535.f + 0.5f);
        }
      }
    }
  }

  __syncthreads();   // all phase-1 LDS reads + ugQ writes complete
#pragma unroll
  for (int rt = 0; rt < 2; ++rt) {
#pragma unroll
    for (int i = 0; i < 4; ++i) {
      int row = rt * 16 + q * 4 + i;
#pragma unroll
      for (int t = 0; t < 2; ++t) {
        int c = t ? c1p : c0p;
        if (c < Uu) {
          float p = pr[t][rt][i];
          u16 hh = f2bf(p);
          ahL[row * AS + c] = hh;
          alL[row * AS + c] = f2bf(p - bf2f(hh));
        }
      }
    }
  }
  __syncthreads();   // cat2 = [r*st | xi] (split) ready in LDS

  // ---- phase 2: c GEMM + blend, 2 passes of 1 tile ----
#pragma unroll
  for (int t = 0; t < 2; ++t) {
    int T = t * 4 + w;
    bf16x8 wh[4], wl[4];
#pragma unroll
    for (int s = 0; s < 4; ++s) {
      const int o = (T * 16 + l15) * Kk + s * 32 + q * 8;
      wh[s] = *(const bf16x8*)(wch + o);
      wl[s] = *(const bf16x8*)(wcl + o);
    }
    f32x4 acc[2];
    acc[0] = zero; acc[1] = zero;
#pragma unroll
    for (int rt = 0; rt < 2; ++rt) {
#pragma unroll
      for (int s = 0; s < 4; ++s) {
        bf16x8 a = *(const bf16x8*)(ahL + (rt * 16 + l15) * AS + s * 32 + q * 8);
        bf16x8 b = *(const bf16x8*)(alL + (rt * 16 + l15) * AS + s * 32 + q * 8);
        acc[rt] = __builtin_amdgcn_mfma_f32_16x16x32_bf16(a, wh[s], acc[rt], 0, 0, 0);
        acc[rt] = __builtin_amdgcn_mfma_f32_16x16x32_bf16(b, wh[s], acc[rt], 0, 0, 0);
        acc[rt] = __builtin_amdgcn_mfma_f32_16x16x32_bf16(a, wl[s], acc[rt], 0, 0, 0);
      }
    }
    int c = t ? c1p : c0p;
    float bv = (c < Uu) ? bc[c] : 0.f;
#pragma unroll
    for (int rt = 0; rt < 2; ++rt) {
#pragma unroll
      for (int i = 0; i < 4; ++i) {
        int row = rt * 16 + q * 4 + i;
        size_t m = (size_t)(m0 + row);
        if (c < Uu) {
          float y = acc[rt][i] + bv;
          float cv = 1.f - 2.f / (__expf(2.f * y) + 1.f);
          float u = (float)ugQ[row * Uu + c] * (1.f / 65535.f);
          out[m * Uu + c] = u * sv[t][rt][i] + (1.f - u) * cv;
        }
      }
    }
  }
}

// ---------------------------------------------------------------------------
extern "C" void kernel_launch(void* const* d_in, const int* in_sizes, int n_in,
                              void* d_out, int out_size, void* d_ws, size_t ws_size,
                              hipStream_t stream) {
  const float* inp   = (const float*)d_in[0];
  const float* stt   = (const float*)d_in[1];
  const int*   esrc  = (const int*)d_in[2];
  const int*   edst  = (const int*)d_in[3];
  const float* Wg    = (const float*)d_in[4];
  const float* att_s = (const float*)d_in[5];
  const float* att_d = (const float*)d_in[6];
  const float* gbias = (const float*)d_in[7];
  const float* b1    = (const float*)d_in[8];
  const float* Wru   = (const float*)d_in[9];
  const float* bru   = (const float*)d_in[10];
  const float* Wc    = (const float*)d_in[11];
  const float* bc    = (const float*)d_in[12];
  float* out = (float*)d_out;

  char* base = (char*)d_ws;
  size_t o = 0;
  auto alloc = [&](size_t bytes) -> void* {
    void* p = base + o;
    o = (o + bytes + 255) & ~(size_t)255;
    return p;
  };
  u16* wgh  = (u16*)alloc(128 * Kk * sizeof(u16));
  u16* wgl  = (u16*)alloc(128 * Kk * sizeof(u16));
  u16* wruh = (u16*)alloc(256 * Kk * sizeof(u16));
  u16* wrul = (u16*)alloc(256 * Kk * sizeof(u16));
  u16* wch  = (u16*)alloc(128 * Kk * sizeof(u16));
  u16* wcl  = (u16*)alloc(128 * Kk * sizeof(u16));
  int* coff  = (int*)alloc((Nn + 1) * sizeof(int));
  int* cslot = (int*)alloc(ET * sizeof(int));
  float* h    = (float*)alloc((size_t)Mrows * Uu * sizeof(float));
  float* asrc = (float*)alloc((size_t)Mrows * sizeof(float));
  float* adst = (float*)alloc((size_t)Mrows * sizeof(float));
  float* gsf  = (float*)alloc((size_t)Mrows * Uu * sizeof(float));
  // total ~47.6 MB — proven footprint

  k_prep<<<32, 256, 0, stream>>>(Wg, Wru, Wc, wgh, wgl, wruh, wrul, wch, wcl);
  k_csr<<<1, 256, 0, stream>>>(esrc, edst, coff, cslot);
  k_gemm1<<<Mrows / 32, 256, 0, stream>>>(stt, inp, wgh, wgl, att_s, att_d, h, asrc, adst);
  k_attn<<<dim3(Bb, 60), 256, 0, stream>>>(coff, cslot, asrc, adst, h, gbias, b1, gsf);
  k_gru<<<Mrows / 32, 256, 0, stream>>>(gsf, inp, wruh, wrul, bru, wch, wcl, bc, out);
}